// Round 1
// baseline (1685.860 us; speedup 1.0000x reference)
//
#include <hip/hip_runtime.h>
#include <stdint.h>

// CodebookWrapperLinear: out = x @ dequant(w)^T
//   x: (8192, 4096) f32 ; codebook: (4,) f32 ; scale: (16384,128,1) f32 ;
//   indexes: (16384,128,32) i32 ; out: (8192, 16384) f32
// Strategy: dequant w -> bf16 (N x K, K-contiguous = B^T layout) and x -> bf16
// into d_ws, then m97-structure bf16 MFMA GEMM (128x128 tile, BK=32,
// global_load_lds width=16, 2 barriers/K-step, XCD-swizzled 1D grid).

typedef unsigned short u16;
typedef __attribute__((ext_vector_type(8))) __bf16 bf16x8;
typedef __attribute__((ext_vector_type(4))) float f32x4;

__device__ __forceinline__ uint32_t f2bf(float f) {
  uint32_t u = __builtin_bit_cast(uint32_t, f);
  return (u + 0x7FFFu + ((u >> 16) & 1u)) >> 16;  // RNE f32 -> bf16
}

__device__ __forceinline__ void gload16(const void* g, void* l) {
  // global -> LDS async copy, 16 B/lane. LDS dest = wave-uniform base + lane*16.
  __builtin_amdgcn_global_load_lds(
      (__attribute__((address_space(1))) void*)(g),
      (__attribute__((address_space(3))) void*)(l), 16, 0, 0);
}

__device__ __forceinline__ uint32_t sel4(uint32_t b0, uint32_t b1, uint32_t b2,
                                         uint32_t b3, int q) {
  // 2-bit codebook select without a runtime-indexed array (avoid scratch).
  uint32_t lo = (q & 1) ? b1 : b0;
  uint32_t hi = (q & 1) ? b3 : b2;
  return (q & 2) ? hi : lo;
}

// ---- x: f32 -> bf16, 8 elems/thread --------------------------------------
__global__ __launch_bounds__(256) void cvt_x(const float* __restrict__ x,
                                             u16* __restrict__ xb, int n8) {
  int t = blockIdx.x * 256 + threadIdx.x;
  if (t >= n8) return;
  const float4* xp = reinterpret_cast<const float4*>(x) + (size_t)t * 2;
  float4 v0 = xp[0], v1 = xp[1];
  uint4 o;
  o.x = f2bf(v0.x) | (f2bf(v0.y) << 16);
  o.y = f2bf(v0.z) | (f2bf(v0.w) << 16);
  o.z = f2bf(v1.x) | (f2bf(v1.y) << 16);
  o.w = f2bf(v1.z) | (f2bf(v1.w) << 16);
  reinterpret_cast<uint4*>(xb)[t] = o;
}

// ---- w dequant: one thread per 32-elem group -----------------------------
__global__ __launch_bounds__(256) void dequant_w(
    const float* __restrict__ cb, const float* __restrict__ scale,
    const int* __restrict__ idx, u16* __restrict__ w, int ngroups) {
  int t = blockIdx.x * 256 + threadIdx.x;
  if (t >= ngroups) return;
  float m = fmaxf(fmaxf(fabsf(cb[0]), fabsf(cb[1])),
                  fmaxf(fabsf(cb[2]), fabsf(cb[3])));
  m = fmaxf(m, 1e-8f);
  float s = expf(scale[t]) / m;  // cb_norm * exp(scale), fused
  uint32_t b0 = f2bf(cb[0] * s), b1 = f2bf(cb[1] * s);
  uint32_t b2 = f2bf(cb[2] * s), b3 = f2bf(cb[3] * s);
  const int4* ip = reinterpret_cast<const int4*>(idx) + (size_t)t * 8;
  uint4* op = reinterpret_cast<uint4*>(w) + (size_t)t * 4;
#pragma unroll
  for (int v = 0; v < 4; ++v) {
    int4 qa = ip[v * 2], qb = ip[v * 2 + 1];
    uint4 o;
    o.x = sel4(b0, b1, b2, b3, qa.x) | (sel4(b0, b1, b2, b3, qa.y) << 16);
    o.y = sel4(b0, b1, b2, b3, qa.z) | (sel4(b0, b1, b2, b3, qa.w) << 16);
    o.z = sel4(b0, b1, b2, b3, qb.x) | (sel4(b0, b1, b2, b3, qb.y) << 16);
    o.w = sel4(b0, b1, b2, b3, qb.z) | (sel4(b0, b1, b2, b3, qb.w) << 16);
    op[v] = o;
  }
}

// ---- m97-structure bf16 GEMM: C[MxN] = A[MxK] * Bt[NxK]^T ----------------
#define BM 128
#define BN 128
#define BK 32

__global__ __launch_bounds__(256) void gemm_bt(
    const u16* __restrict__ A, const u16* __restrict__ Bt,
    float* __restrict__ C, int M, int N, int K) {
  __shared__ u16 sA[BM * BK];  // 8 KiB, linear row-major [128][32]
  __shared__ u16 sB[BN * BK];  // 8 KiB

  // XCD-aware bijective swizzle (gridDim.x % 8 == 0 here)
  const int nwg = gridDim.x;
  const int cpx = nwg >> 3;
  const int bid = blockIdx.x;
  const int swz = (bid & 7) * cpx + (bid >> 3);
  const int ntn = N / BN;
  const int m0 = (swz / ntn) * BM;
  const int n0 = (swz % ntn) * BN;

  const int tid = threadIdx.x;
  const int lane = tid & 63;
  const int wid = tid >> 6;     // 4 waves, 2x2 wave grid, 64x64 out each
  const int wr = wid >> 1;
  const int wc = wid & 1;

  // staging: LDS byte L = it*4096 + wid*1024 + lane*16
  //   -> row = it*64 + wid*16 + lane/4 , col = (lane&3)*8
  const int srow = wid * 16 + (lane >> 2);
  const int scol = (lane & 3) * 8;
  const u16* gA = A + (size_t)(m0 + srow) * K + scol;
  const u16* gB = Bt + (size_t)(n0 + srow) * K + scol;
  u16* lA = sA + wid * 512;  // elements (wave-uniform base)
  u16* lB = sB + wid * 512;

  // fragment reads: A row = lane&15 (k-contiguous 8), B col = lane&15
  const int lr = lane & 15;
  const int lk = (lane >> 4) * 8;
  const u16* rA = sA + (wr * 64 + lr) * BK + lk;
  const u16* rB = sB + (wc * 64 + lr) * BK + lk;

  f32x4 acc[4][4];
#pragma unroll
  for (int i = 0; i < 4; ++i)
#pragma unroll
    for (int j = 0; j < 4; ++j) acc[i][j] = f32x4{0.f, 0.f, 0.f, 0.f};

  const int nk = K / BK;
  for (int kt = 0; kt < nk; ++kt) {
    gload16(gA, lA);
    gload16(gA + (size_t)64 * K, lA + 2048);
    gload16(gB, lB);
    gload16(gB + (size_t)64 * K, lB + 2048);
    gA += BK;
    gB += BK;
    __syncthreads();  // compiler emits vmcnt(0) drain -> tiles visible

    bf16x8 av[4], bv[4];
#pragma unroll
    for (int i = 0; i < 4; ++i)
      av[i] = *reinterpret_cast<const bf16x8*>(rA + i * 16 * BK);
#pragma unroll
    for (int i = 0; i < 4; ++i)
      bv[i] = *reinterpret_cast<const bf16x8*>(rB + i * 16 * BK);
#pragma unroll
    for (int i = 0; i < 4; ++i)
#pragma unroll
      for (int j = 0; j < 4; ++j)
        acc[i][j] = __builtin_amdgcn_mfma_f32_16x16x32_bf16(av[i], bv[j],
                                                            acc[i][j], 0, 0, 0);
    __syncthreads();  // all reads done before next stage overwrites
  }

  // C/D layout (m89-verified): col = lane&15, row = (lane>>4)*4 + reg
  const int crow = m0 + wr * 64 + (lane >> 4) * 4;
  const int ccol = n0 + wc * 64 + (lane & 15);
#pragma unroll
  for (int i = 0; i < 4; ++i)
#pragma unroll
    for (int r = 0; r < 4; ++r) {
      float* cp = C + (size_t)(crow + i * 16 + r) * N + ccol;
#pragma unroll
      for (int j = 0; j < 4; ++j) cp[j * 16] = acc[i][j][r];
    }
}

extern "C" void kernel_launch(void* const* d_in, const int* in_sizes, int n_in,
                              void* d_out, int out_size, void* d_ws,
                              size_t ws_size, hipStream_t stream) {
  const float* x = (const float*)d_in[0];
  const float* cb = (const float*)d_in[1];
  const float* scale = (const float*)d_in[2];
  const int* idx = (const int*)d_in[3];
  float* out = (float*)d_out;

  constexpr int M = 4 * 2048;  // B*S
  constexpr int N = 16384;     // OUT
  constexpr int K = 4096;      // IN

  u16* xb = (u16*)d_ws;             // M*K bf16 = 64 MiB
  u16* wb = xb + (size_t)M * K;     // N*K bf16 = 128 MiB

  const int n8 = M * K / 8;
  cvt_x<<<dim3(n8 / 256), dim3(256), 0, stream>>>(x, xb, n8);
  const int ngroups = N * (K / 32);
  dequant_w<<<dim3(ngroups / 256), dim3(256), 0, stream>>>(cb, scale, idx, wb,
                                                           ngroups);
  gemm_bt<<<dim3((M / BM) * (N / BN)), dim3(256), 0, stream>>>(xb, wb, out, M,
                                                               N, K);
}

// Round 2
// 1117.779 us; speedup vs baseline: 1.5082x; 1.5082x over previous
//
#include <hip/hip_runtime.h>
#include <stdint.h>

// CodebookWrapperLinear: out = x @ dequant(w)^T
//   x: (8192,4096) f32 ; codebook: (4,) f32 ; scale: (16384,128,1) f32 ;
//   indexes: (16384,128,32) i32 ; out: (8192,16384) f32
// R2: 256x256 8-phase bf16 GEMM (T1 XCD swizzle + T2 LDS XOR swizzle +
// T3/T4 phase interleave w/ late vmcnt + T5 setprio). Prefetch depth = 1
// K-tile, front-loaded in phases 1-2, so the single vmcnt(0) per K-tile
// waits on ~2.5-phase-old loads (counted-wait equivalent, race-free).

typedef unsigned short u16;
typedef __attribute__((ext_vector_type(8))) __bf16 bf16x8;
typedef __attribute__((ext_vector_type(4))) float f32x4;

__device__ __forceinline__ uint32_t f2bf(float f) {
  uint32_t u = __builtin_bit_cast(uint32_t, f);
  return (u + 0x7FFFu + ((u >> 16) & 1u)) >> 16;  // RNE f32 -> bf16
}

__device__ __forceinline__ void gload16(const u16* g, u16* l) {
  __builtin_amdgcn_global_load_lds(
      (__attribute__((address_space(1))) void*)(g),
      (__attribute__((address_space(3))) void*)(l), 16, 0, 0);
}

__device__ __forceinline__ uint32_t sel4(uint32_t b0, uint32_t b1, uint32_t b2,
                                         uint32_t b3, int q) {
  uint32_t lo = (q & 1) ? b1 : b0;
  uint32_t hi = (q & 1) ? b3 : b2;
  return (q & 2) ? hi : lo;
}

// ---- x: f32 -> bf16, 8 elems/thread --------------------------------------
__global__ __launch_bounds__(256) void cvt_x(const float* __restrict__ x,
                                             u16* __restrict__ xb, int n8) {
  int t = blockIdx.x * 256 + threadIdx.x;
  if (t >= n8) return;
  const float4* xp = reinterpret_cast<const float4*>(x) + (size_t)t * 2;
  float4 v0 = xp[0], v1 = xp[1];
  uint4 o;
  o.x = f2bf(v0.x) | (f2bf(v0.y) << 16);
  o.y = f2bf(v0.z) | (f2bf(v0.w) << 16);
  o.z = f2bf(v1.x) | (f2bf(v1.y) << 16);
  o.w = f2bf(v1.z) | (f2bf(v1.w) << 16);
  reinterpret_cast<uint4*>(xb)[t] = o;
}

// ---- w dequant: one thread per 32-elem group -----------------------------
__global__ __launch_bounds__(256) void dequant_w(
    const float* __restrict__ cb, const float* __restrict__ scale,
    const int* __restrict__ idx, u16* __restrict__ w, int ngroups) {
  int t = blockIdx.x * 256 + threadIdx.x;
  if (t >= ngroups) return;
  float m = fmaxf(fmaxf(fabsf(cb[0]), fabsf(cb[1])),
                  fmaxf(fabsf(cb[2]), fabsf(cb[3])));
  m = fmaxf(m, 1e-8f);
  float s = expf(scale[t]) / m;
  uint32_t b0 = f2bf(cb[0] * s), b1 = f2bf(cb[1] * s);
  uint32_t b2 = f2bf(cb[2] * s), b3 = f2bf(cb[3] * s);
  const int4* ip = reinterpret_cast<const int4*>(idx) + (size_t)t * 8;
  uint4* op = reinterpret_cast<uint4*>(w) + (size_t)t * 4;
#pragma unroll
  for (int v = 0; v < 4; ++v) {
    int4 qa = ip[v * 2], qb = ip[v * 2 + 1];
    uint4 o;
    o.x = sel4(b0, b1, b2, b3, qa.x) | (sel4(b0, b1, b2, b3, qa.y) << 16);
    o.y = sel4(b0, b1, b2, b3, qa.z) | (sel4(b0, b1, b2, b3, qa.w) << 16);
    o.z = sel4(b0, b1, b2, b3, qb.x) | (sel4(b0, b1, b2, b3, qb.y) << 16);
    o.w = sel4(b0, b1, b2, b3, qb.z) | (sel4(b0, b1, b2, b3, qb.w) << 16);
    op[v] = o;
  }
}

// ---- 256x256 8-phase bf16 GEMM: C[MxN] = A[MxK] * Bt[NxK]^T --------------
#define BM 256
#define BN 256
#define BK 64

__device__ __forceinline__ void memfence() { asm volatile("" ::: "memory"); }
__device__ __forceinline__ void BAR() {
  memfence();
  __builtin_amdgcn_s_barrier();
  memfence();
}

__global__ void __launch_bounds__(512, 2) gemm256(
    const u16* __restrict__ A, const u16* __restrict__ Bt,
    float* __restrict__ C, int M, int N, int K) {
  // [dbuf][A|B][256 rows x 64 cols] bf16 = 128 KiB
  __shared__ u16 sm[2][2][BM * BK];

  // T1: XCD-aware bijective swizzle (gridDim.x = 2048, %8 == 0)
  const int nwg = gridDim.x;
  const int cpx = nwg >> 3;
  const int bid = blockIdx.x;
  const int swz = (bid & 7) * cpx + (bid >> 3);
  const int ntn = N / BN;
  const int m0 = (swz / ntn) * BM;
  const int n0 = (swz % ntn) * BN;

  const int tid = threadIdx.x;
  const int lane = tid & 63;
  const int wid = tid >> 6;  // 8 waves: 2 (m) x 4 (n)
  const int wr = wid >> 2;   // wave row: owns 128 rows
  const int wc = wid & 3;    // wave col: owns 64 cols

  // ---- staging: linear LDS dest (base + lane*16), pre-swizzled global src.
  // LDS row R = wid*8 + (lane>>3) + r*64 + h*128 ; physical 16B-slot = lane&7.
  // Invariant: LDS (R, p) holds global (R, p ^ (R&7)); R&7 == (lane>>3)&7.
  const int srow = wid * 8 + (lane >> 3);
  const int scol = (((lane & 7) ^ ((lane >> 3) & 7)) << 3);
  const u16* gA = A + (size_t)(m0 + srow) * K + scol;
  const u16* gB = Bt + (size_t)(n0 + srow) * K + scol;
  const size_t rs = (size_t)64 * K;  // 64-row source step

#define STAGE_A(b)                          \
  {                                         \
    u16* d = &sm[(b)][0][wid * 512];        \
    gload16(gA, d);                         \
    gload16(gA + rs, d + 4096);             \
    gload16(gA + 2 * rs, d + 8192);         \
    gload16(gA + 3 * rs, d + 12288);        \
  }
#define STAGE_B(b)                          \
  {                                         \
    u16* d = &sm[(b)][1][wid * 512];        \
    gload16(gB, d);                         \
    gload16(gB + rs, d + 4096);             \
    gload16(gB + 2 * rs, d + 8192);         \
    gload16(gB + 3 * rs, d + 12288);        \
  }

  // ---- swizzled LDS read addressing -------------------------------------
  // logical slot for kslice ks, lane: ks*4 + (lane>>4); physical = ^ (row&7),
  // row&7 == lane&7. 64 lanes spread over all 8 slots -> 2-way max (free).
  const int swzp0 = (((lane >> 4) ^ (lane & 7)) << 3);
  const int swzp1 = ((((lane >> 4) + 4) ^ (lane & 7)) << 3);
  const int rArow = (wr * 128 + (lane & 15)) * BK;
  const int rBrow = (wc * 64 + (lane & 15)) * BK;

  bf16x8 af[4][2], bv[2][2];

#define LOADA(b, q)                                                    \
  {                                                                    \
    const u16* p = &sm[(b)][0][rArow + (q) * 4096];                    \
    af[0][0] = *(const bf16x8*)(p + swzp0);                            \
    af[0][1] = *(const bf16x8*)(p + swzp1);                            \
    af[1][0] = *(const bf16x8*)(p + 1024 + swzp0);                     \
    af[1][1] = *(const bf16x8*)(p + 1024 + swzp1);                     \
    af[2][0] = *(const bf16x8*)(p + 2048 + swzp0);                     \
    af[2][1] = *(const bf16x8*)(p + 2048 + swzp1);                     \
    af[3][0] = *(const bf16x8*)(p + 3072 + swzp0);                     \
    af[3][1] = *(const bf16x8*)(p + 3072 + swzp1);                     \
  }
#define LOADB(b, pp)                                                   \
  {                                                                    \
    const u16* p = &sm[(b)][1][rBrow + (pp) * 2048];                   \
    bv[0][0] = *(const bf16x8*)(p + swzp0);                            \
    bv[0][1] = *(const bf16x8*)(p + swzp1);                            \
    bv[1][0] = *(const bf16x8*)(p + 1024 + swzp0);                     \
    bv[1][1] = *(const bf16x8*)(p + 1024 + swzp1);                     \
  }
#define MFMAQ(q, pp)                                                   \
  {                                                                    \
    __builtin_amdgcn_s_setprio(1);                                     \
    _Pragma("unroll") for (int i = 0; i < 4; ++i)                      \
        _Pragma("unroll") for (int j = 0; j < 2; ++j)                  \
            _Pragma("unroll") for (int ks = 0; ks < 2; ++ks)           \
                acc[(q) * 4 + i][(pp) * 2 + j] =                       \
        __builtin_amdgcn_mfma_f32_16x16x32_bf16(                       \
            af[i][ks], bv[j][ks], acc[(q) * 4 + i][(pp) * 2 + j], 0, 0, 0); \
    __builtin_amdgcn_s_setprio(0);                                     \
  }

  f32x4 acc[8][4];
#pragma unroll
  for (int i = 0; i < 8; ++i)
#pragma unroll
    for (int j = 0; j < 4; ++j) acc[i][j] = f32x4{0.f, 0.f, 0.f, 0.f};

  const int nk = K / BK;

  // prologue: stage K-tile 0 -> buf0
  STAGE_A(0)
  STAGE_B(0)
  gA += BK;
  gB += BK;
  asm volatile("s_waitcnt vmcnt(0)" ::: "memory");
  __builtin_amdgcn_s_barrier();
  memfence();

  for (int t = 0; t < nk; ++t) {
    const int cu = t & 1;
    const int nx = cu ^ 1;
    const bool pf = (t + 1 < nk);
    // phase 1: quadrant (m 0-3, n 0-1); front-load A prefetch of t+1
    LOADA(cu, 0)
    LOADB(cu, 0)
    if (pf) STAGE_A(nx)
    BAR();
    MFMAQ(0, 0)
    BAR();
    // phase 2: quadrant (m 0-3, n 2-3); front-load B prefetch of t+1
    LOADB(cu, 1)
    if (pf) {
      STAGE_B(nx)
      gA += BK;
      gB += BK;
    }
    BAR();
    MFMAQ(0, 1)
    BAR();
    // phase 3: quadrant (m 4-7, n 2-3)
    LOADA(cu, 1)
    BAR();
    MFMAQ(1, 1)
    BAR();
    // phase 4: quadrant (m 4-7, n 0-1); drain prefetch (loads ~3 phases old)
    LOADB(cu, 0)
    BAR();
    MFMAQ(1, 0)
    asm volatile("s_waitcnt vmcnt(0)" ::: "memory");
    BAR();
  }

  // epilogue: C/D layout col=lane&15, row=(lane>>4)*4+reg
  const int crow0 = m0 + wr * 128 + ((lane >> 4) << 2);
  const int ccol = n0 + wc * 64 + (lane & 15);
#pragma unroll
  for (int mi = 0; mi < 8; ++mi)
#pragma unroll
    for (int r = 0; r < 4; ++r) {
      float* cp = C + (size_t)(crow0 + mi * 16 + r) * N + ccol;
#pragma unroll
      for (int ni = 0; ni < 4; ++ni) cp[ni * 16] = acc[mi][ni][r];
    }
}

extern "C" void kernel_launch(void* const* d_in, const int* in_sizes, int n_in,
                              void* d_out, int out_size, void* d_ws,
                              size_t ws_size, hipStream_t stream) {
  const float* x = (const float*)d_in[0];
  const float* cb = (const float*)d_in[1];
  const float* scale = (const float*)d_in[2];
  const int* idx = (const int*)d_in[3];
  float* out = (float*)d_out;

  constexpr int M = 4 * 2048;  // B*S
  constexpr int N = 16384;     // OUT
  constexpr int K = 4096;      // IN

  u16* xb = (u16*)d_ws;          // M*K bf16 = 64 MiB
  u16* wb = xb + (size_t)M * K;  // N*K bf16 = 128 MiB

  const int n8 = M * K / 8;
  cvt_x<<<dim3(n8 / 256), dim3(256), 0, stream>>>(x, xb, n8);
  const int ngroups = N * (K / 32);
  dequant_w<<<dim3(ngroups / 256), dim3(256), 0, stream>>>(cb, scale, idx, wb,
                                                           ngroups);
  gemm256<<<dim3((M / BM) * (N / BN)), dim3(512), 0, stream>>>(xb, wb, out, M,
                                                               N, K);
}

// Round 3
// 1053.912 us; speedup vs baseline: 1.5996x; 1.0606x over previous
//
#include <hip/hip_runtime.h>
#include <stdint.h>

// CodebookWrapperLinear: out = x @ dequant(w)^T
//   x: (8192,4096) f32 ; codebook: (4,) f32 ; scale: (16384,128,1) f32 ;
//   indexes: (16384,128,32) i32 ; out: (8192,16384) f32
// R3: true m201-style 8-phase schedule: 1 half-tile stage per phase,
// counted s_waitcnt vmcnt(6) at phases 4/8 only (never drain-0 in loop).
// Ledger-verified: W4 guarantees tile 2i+1 (staged S6-S8 prev + S1 this),
// W8 guarantees tile 2i+2 (staged S2-S5 this); every stage targets an LDS
// half whose last ds_read was >=1 phase (2 barriers) earlier.

typedef unsigned short u16;
typedef __attribute__((ext_vector_type(8))) __bf16 bf16x8;
typedef __attribute__((ext_vector_type(4))) float f32x4;

__device__ __forceinline__ uint32_t f2bf(float f) {
  uint32_t u = __builtin_bit_cast(uint32_t, f);
  return (u + 0x7FFFu + ((u >> 16) & 1u)) >> 16;  // RNE f32 -> bf16
}

__device__ __forceinline__ void gload16(const u16* g, u16* l) {
  __builtin_amdgcn_global_load_lds(
      (__attribute__((address_space(1))) void*)(g),
      (__attribute__((address_space(3))) void*)(l), 16, 0, 0);
}

__device__ __forceinline__ uint32_t sel4(uint32_t b0, uint32_t b1, uint32_t b2,
                                         uint32_t b3, int q) {
  uint32_t lo = (q & 1) ? b1 : b0;
  uint32_t hi = (q & 1) ? b3 : b2;
  return (q & 2) ? hi : lo;
}

// ---- x: f32 -> bf16, 8 elems/thread --------------------------------------
__global__ __launch_bounds__(256) void cvt_x(const float* __restrict__ x,
                                             u16* __restrict__ xb, int n8) {
  int t = blockIdx.x * 256 + threadIdx.x;
  if (t >= n8) return;
  const float4* xp = reinterpret_cast<const float4*>(x) + (size_t)t * 2;
  float4 v0 = xp[0], v1 = xp[1];
  uint4 o;
  o.x = f2bf(v0.x) | (f2bf(v0.y) << 16);
  o.y = f2bf(v0.z) | (f2bf(v0.w) << 16);
  o.z = f2bf(v1.x) | (f2bf(v1.y) << 16);
  o.w = f2bf(v1.z) | (f2bf(v1.w) << 16);
  reinterpret_cast<uint4*>(xb)[t] = o;
}

// ---- w dequant: one thread per 32-elem group -----------------------------
__global__ __launch_bounds__(256) void dequant_w(
    const float* __restrict__ cb, const float* __restrict__ scale,
    const int* __restrict__ idx, u16* __restrict__ w, int ngroups) {
  int t = blockIdx.x * 256 + threadIdx.x;
  if (t >= ngroups) return;
  float m = fmaxf(fmaxf(fabsf(cb[0]), fabsf(cb[1])),
                  fmaxf(fabsf(cb[2]), fabsf(cb[3])));
  m = fmaxf(m, 1e-8f);
  float s = expf(scale[t]) / m;
  uint32_t b0 = f2bf(cb[0] * s), b1 = f2bf(cb[1] * s);
  uint32_t b2 = f2bf(cb[2] * s), b3 = f2bf(cb[3] * s);
  const int4* ip = reinterpret_cast<const int4*>(idx) + (size_t)t * 8;
  uint4* op = reinterpret_cast<uint4*>(w) + (size_t)t * 4;
#pragma unroll
  for (int v = 0; v < 4; ++v) {
    int4 qa = ip[v * 2], qb = ip[v * 2 + 1];
    uint4 o;
    o.x = sel4(b0, b1, b2, b3, qa.x) | (sel4(b0, b1, b2, b3, qa.y) << 16);
    o.y = sel4(b0, b1, b2, b3, qa.z) | (sel4(b0, b1, b2, b3, qa.w) << 16);
    o.z = sel4(b0, b1, b2, b3, qb.x) | (sel4(b0, b1, b2, b3, qb.y) << 16);
    o.w = sel4(b0, b1, b2, b3, qb.z) | (sel4(b0, b1, b2, b3, qb.w) << 16);
    op[v] = o;
  }
}

// ---- 256x256 8-phase bf16 GEMM: C[MxN] = A[MxK] * Bt[NxK]^T --------------
#define BM 256
#define BN 256
#define BK 64

__device__ __forceinline__ void memfence() { asm volatile("" ::: "memory"); }
__device__ __forceinline__ void BARx() {
  memfence();
  __builtin_amdgcn_s_barrier();
  memfence();
}

__global__ void __launch_bounds__(512, 2) gemm256(
    const u16* __restrict__ A, const u16* __restrict__ Bt,
    float* __restrict__ C, int M, int N, int K) {
  // [buf: even/odd K-tile][A|B][256 rows x 64 cols] bf16 = 128 KiB
  __shared__ u16 sm[2][2][BM * BK];

  // T1: XCD-aware bijective swizzle (gridDim.x = 2048, %8 == 0)
  const int nwg = gridDim.x;
  const int cpx = nwg >> 3;
  const int bid = blockIdx.x;
  const int swz = (bid & 7) * cpx + (bid >> 3);
  const int ntn = N / BN;
  const int m0 = (swz / ntn) * BM;
  const int n0 = (swz % ntn) * BN;

  const int tid = threadIdx.x;
  const int lane = tid & 63;
  const int wid = tid >> 6;  // 8 waves: 2 (m: wr) x 4 (n: wc)
  const int wr = wid >> 2;
  const int wc = wid & 3;

  // staging: linear LDS dest (base + lane*16), pre-swizzled global source.
  // LDS (row R, slot p) holds global (row R, slot p ^ (R&7)); R&7=(lane>>3)&7.
  const int srow = wid * 8 + (lane >> 3);
  const int scol = (((lane & 7) ^ ((lane >> 3) & 7)) << 3);
  const u16* gA = A + (size_t)(m0 + srow) * K + scol;
  const u16* gB = Bt + (size_t)(n0 + srow) * K + scol;

  // STAGE one contiguous 128-row half: op 0=A 1=B, h = half, kc = K-col offset
#define STAGE(b, op, h, gp, kc)                                   \
  {                                                               \
    u16* d = &sm[(b)][(op)][(h)*8192 + wid * 512];                \
    const u16* g = (gp) + (size_t)((h)*128) * K + (kc);           \
    gload16(g, d);                                                \
    gload16(g + (size_t)64 * K, d + 4096);                        \
  }

  // swizzled LDS fragment reads: row&7 == lane&7 for all fragment rows
  const int swzp0 = (((lane >> 4) ^ (lane & 7)) << 3);
  const int swzp1 = ((((lane >> 4) + 4) ^ (lane & 7)) << 3);
  const int lr = lane & 15;
  const int rAbase = (wr * 64 + lr) * BK;  // + q*8192 selects A half
  const int rBbase = (wc * 32 + lr) * BK;  // + pp*8192 selects B half

  bf16x8 af[4][2], bv[2][2];

#define LOADA(b, q)                                               \
  {                                                               \
    const u16* p = &sm[(b)][0][rAbase + (q)*8192];                \
    af[0][0] = *(const bf16x8*)(p + swzp0);                       \
    af[0][1] = *(const bf16x8*)(p + swzp1);                       \
    af[1][0] = *(const bf16x8*)(p + 1024 + swzp0);                \
    af[1][1] = *(const bf16x8*)(p + 1024 + swzp1);                \
    af[2][0] = *(const bf16x8*)(p + 2048 + swzp0);                \
    af[2][1] = *(const bf16x8*)(p + 2048 + swzp1);                \
    af[3][0] = *(const bf16x8*)(p + 3072 + swzp0);                \
    af[3][1] = *(const bf16x8*)(p + 3072 + swzp1);                \
  }
#define LOADB(b, pp)                                              \
  {                                                               \
    const u16* p = &sm[(b)][1][rBbase + (pp)*8192];               \
    bv[0][0] = *(const bf16x8*)(p + swzp0);                       \
    bv[0][1] = *(const bf16x8*)(p + swzp1);                       \
    bv[1][0] = *(const bf16x8*)(p + 1024 + swzp0);                \
    bv[1][1] = *(const bf16x8*)(p + 1024 + swzp1);                \
  }
#define MFMAQ(q, pp)                                                        \
  {                                                                         \
    __builtin_amdgcn_s_setprio(1);                                          \
    _Pragma("unroll") for (int i = 0; i < 4; ++i)                           \
        _Pragma("unroll") for (int j = 0; j < 2; ++j)                       \
            _Pragma("unroll") for (int ks = 0; ks < 2; ++ks)                \
                acc[(q)*4 + i][(pp)*2 + j] =                                \
        __builtin_amdgcn_mfma_f32_16x16x32_bf16(                            \
            af[i][ks], bv[j][ks], acc[(q)*4 + i][(pp)*2 + j], 0, 0, 0);     \
    __builtin_amdgcn_s_setprio(0);                                          \
  }
#define VM6 asm volatile("s_waitcnt vmcnt(6)" ::: "memory");
#define VM0 asm volatile("s_waitcnt vmcnt(0)" ::: "memory");

  f32x4 acc[8][4];
#pragma unroll
  for (int i = 0; i < 8; ++i)
#pragma unroll
    for (int j = 0; j < 4; ++j) acc[i][j] = f32x4{0.f, 0.f, 0.f, 0.f};

  // ---- prologue: tile0 (all 4 halves) then tile1 (A0,B1,A1) -------------
  STAGE(0, 0, 0, gA, (size_t)0)    // P1 A0(b0) t0
  STAGE(0, 1, 1, gB, (size_t)0)    // P2 B1(b0) t0
  STAGE(0, 0, 1, gA, (size_t)0)    // P3 A1(b0) t0
  STAGE(0, 1, 0, gB, (size_t)0)    // P4 B0(b0) t0
  STAGE(1, 0, 0, gA, (size_t)64)   // P5 A0(b1) t1
  STAGE(1, 1, 1, gB, (size_t)64)   // P6 B1(b1) t1
  STAGE(1, 0, 1, gA, (size_t)64)   // P7 A1(b1) t1
  VM6  // tile0's 8 loads are the 8 oldest of 14 -> guaranteed landed
  BARx();

  // ---- main loop: iter i handles tiles 2i (b0), 2i+1 (b1) ---------------
  // nk = K/BK = 64 tiles -> iters 0..31; last iter peeled (no far stages).
#pragma unroll 1
  for (int i = 0; i < 31; ++i) {
    const size_t cS1 = (size_t)(2 * i + 1) * 64;  // tile 2i+1 (B0 half late)
    const size_t cb0 = (size_t)(2 * i + 2) * 64;  // tile 2i+2 -> b0
    const size_t cb1 = (size_t)(2 * i + 3) * 64;  // tile 2i+3 -> b1
    // ph1: reads A0(b0),B0(b0); S1: B0(b1) of tile 2i+1
    LOADA(0, 0) LOADB(0, 0)
    STAGE(1, 1, 0, gB, cS1)
    BARx(); MFMAQ(0, 0) BARx();
    // ph2: reads B1(b0) (af reused); S2: A0(b0) tile 2i+2
    LOADB(0, 1)
    STAGE(0, 0, 0, gA, cb0)
    BARx(); MFMAQ(0, 1) BARx();
    // ph3: reads A1(b0) (bv reused); S3: B1(b0)
    LOADA(0, 1)
    STAGE(0, 1, 1, gB, cb0)
    BARx(); MFMAQ(1, 1) BARx();
    // ph4: re-reads B0(b0); S4: A1(b0); W4: tile 2i+1 guaranteed
    LOADB(0, 0)
    STAGE(0, 0, 1, gA, cb0)
    BARx(); MFMAQ(1, 0) VM6 BARx();
    // ph5: reads A0(b1),B0(b1); S5: B0(b0)
    LOADA(1, 0) LOADB(1, 0)
    STAGE(0, 1, 0, gB, cb0)
    BARx(); MFMAQ(0, 0) BARx();
    // ph6: reads B1(b1); S6: A0(b1) tile 2i+3
    LOADB(1, 1)
    STAGE(1, 0, 0, gA, cb1)
    BARx(); MFMAQ(0, 1) BARx();
    // ph7: reads A1(b1); S7: B1(b1)
    LOADA(1, 1)
    STAGE(1, 1, 1, gB, cb1)
    BARx(); MFMAQ(1, 1) BARx();
    // ph8: re-reads B0(b1); S8: A1(b1); W8: tile 2i+2 guaranteed
    LOADB(1, 0)
    STAGE(1, 0, 1, gA, cb1)
    BARx(); MFMAQ(1, 0) VM6 BARx();
  }

  // ---- peeled final iter (tiles 62, 63): only S1; VM0 at W4 -------------
  {
    const size_t cS1 = (size_t)63 * 64;
    LOADA(0, 0) LOADB(0, 0)
    STAGE(1, 1, 0, gB, cS1)
    BARx(); MFMAQ(0, 0) BARx();
    LOADB(0, 1)
    BARx(); MFMAQ(0, 1) BARx();
    LOADA(0, 1)
    BARx(); MFMAQ(1, 1) BARx();
    LOADB(0, 0)
    BARx(); MFMAQ(1, 0) VM0 BARx();
    LOADA(1, 0) LOADB(1, 0)
    BARx(); MFMAQ(0, 0) BARx();
    LOADB(1, 1)
    BARx(); MFMAQ(0, 1) BARx();
    LOADA(1, 1)
    BARx(); MFMAQ(1, 1) BARx();
    LOADB(1, 0)
    BARx(); MFMAQ(1, 0)
  }

  // ---- epilogue: C/D layout col=lane&15, row=(lane>>4)*4+reg ------------
  // wave tile: rows {q*128 + wr*64 + ...}, cols {pp*128 + wc*32 + ...}
  const int crow0 = m0 + wr * 64 + ((lane >> 4) << 2);
  const int ccol0 = n0 + wc * 32 + (lane & 15);
#pragma unroll
  for (int q = 0; q < 2; ++q)
#pragma unroll
    for (int mi = 0; mi < 4; ++mi)
#pragma unroll
      for (int r = 0; r < 4; ++r) {
        float* cp = C + (size_t)(crow0 + q * 128 + mi * 16 + r) * N + ccol0;
#pragma unroll
        for (int pp = 0; pp < 2; ++pp)
#pragma unroll
          for (int j = 0; j < 2; ++j)
            cp[pp * 128 + j * 16] = acc[q * 4 + mi][pp * 2 + j][r];
      }
}

extern "C" void kernel_launch(void* const* d_in, const int* in_sizes, int n_in,
                              void* d_out, int out_size, void* d_ws,
                              size_t ws_size, hipStream_t stream) {
  const float* x = (const float*)d_in[0];
  const float* cb = (const float*)d_in[1];
  const float* scale = (const float*)d_in[2];
  const int* idx = (const int*)d_in[3];
  float* out = (float*)d_out;

  constexpr int M = 4 * 2048;  // B*S
  constexpr int N = 16384;     // OUT
  constexpr int K = 4096;      // IN

  u16* xb = (u16*)d_ws;          // M*K bf16 = 64 MiB
  u16* wb = xb + (size_t)M * K;  // N*K bf16 = 128 MiB

  const int n8 = M * K / 8;
  cvt_x<<<dim3(n8 / 256), dim3(256), 0, stream>>>(x, xb, n8);
  const int ngroups = N * (K / 32);
  dequant_w<<<dim3(ngroups / 256), dim3(256), 0, stream>>>(cb, scale, idx, wb,
                                                           ngroups);
  gemm256<<<dim3((M / BM) * (N / BN)), dim3(512), 0, stream>>>(xb, wb, out, M,
                                                               N, K);
}